// Round 5
// baseline (115.472 us; speedup 1.0000x reference)
//
#include <hip/hip_runtime.h>

#define B_SZ  16384
#define F_SZ  20
#define V_SZ  100000
#define E_SZ  32
#define DBOT  640
#define D1    512
#define D2    256
#define T1D   128
#define T2D   64
#define NDOM  4

typedef __bf16 bf16x8 __attribute__((ext_vector_type(8)));
typedef float  f32x4  __attribute__((ext_vector_type(4)));

#define MFMA(a, b, c) __builtin_amdgcn_mfma_f32_16x16x32_bf16((a), (b), (c), 0, 0, 0)

// Soft grid barrier: valid because grid==256==#CUs and 87KB LDS forces
// 1 block/CU -> all blocks co-resident.  Device-scope atomics + fences.
__device__ __forceinline__ void grid_barrier(int* bar) {
  __syncthreads();
  if (threadIdx.x == 0) {
    __threadfence();
    atomicAdd(bar, 1);
    while (__hip_atomic_load(bar, __ATOMIC_ACQUIRE, __HIP_MEMORY_SCOPE_AGENT) < 256) {
      __builtin_amdgcn_s_sleep(2);
    }
    __threadfence();
  }
  __syncthreads();
}

// ---------------------------------------------------------------------------
// Mono-kernel: phase0 (weight pack + domain partition) -> grid barrier ->
// phase1 (gather + GEMM1 + GEMM2, 64-row panels) -> grid barrier ->
// phase2 (domain towers + sigmoid).
// 256 blocks x 512 threads, 87KB LDS (1 block/CU).
// ---------------------------------------------------------------------------
__global__ __launch_bounds__(512) void k_mono(const int* __restrict__ fids,
                                              const int* __restrict__ dom,
                                              const float* __restrict__ emb,
                                              const float* __restrict__ W1,
                                              const float* __restrict__ b1,
                                              const float* __restrict__ W2,
                                              const float* __restrict__ b2,
                                              const float* __restrict__ TW1,
                                              const float* __restrict__ Tb1,
                                              const float* __restrict__ TW2,
                                              const float* __restrict__ Tb2,
                                              const float* __restrict__ TW3,
                                              const float* __restrict__ Tb3,
                                              __bf16* __restrict__ W1P,
                                              __bf16* __restrict__ W2P,
                                              __bf16* __restrict__ TW1P,
                                              __bf16* __restrict__ TW2P,
                                              __bf16* __restrict__ h2,
                                              int* __restrict__ lists,
                                              int* __restrict__ cnt,
                                              int* __restrict__ bar,
                                              float* __restrict__ out) {
  __shared__ __attribute__((aligned(16))) char smem[87040];
  int*    ids_lds = (int*)smem;                 // 64*20*4  = 5120
  __bf16* sA      = (__bf16*)(smem + 5120);     // 2*64*64*2 = 16384
  __bf16* h1      = (__bf16*)(smem + 21504);    // 64*512*2 = 65536
  __bf16* t_lds   = (__bf16*)smem;              // phase2: 8*2048*2 = 32768

  int bid = blockIdx.x, tid = threadIdx.x;
  int lane = tid & 63, w = tid >> 6;            // w in [0,8)
  int lrow = lane & 15, kq = lane >> 4;

  // ================= phase 0: weight pack + partition =================
  {
    int t = bid * 512 + tid;
    if (t < 77824) {
      const float* src; __bf16* dst; int n, k, N;
      if (t < 40960) {            // W1P: K=640 (20 ksteps), N=512 (32 ntiles)
        int g = t;
        int l = g & 63, kkg = (g >> 6) % 20, ntile = g / 1280;
        n = ntile * 16 + (l & 15); k = kkg * 32 + ((l >> 4) << 3);
        src = W1; N = D1; dst = W1P + (long)g * 8;
      } else if (t < 57344) {     // W2P: K=512 (16), N=256 (16)
        int g = t - 40960;
        int l = g & 63, kkg = (g >> 6) & 15, ntile = g >> 10;
        n = ntile * 16 + (l & 15); k = kkg * 32 + ((l >> 4) << 3);
        src = W2; N = D2; dst = W2P + (long)g * 8;
      } else if (t < 73728) {     // TW1P: per-domain K=256 (8), N=128 (8)
        int g = t - 57344;
        int d = g >> 12, r = g & 4095;
        int l = r & 63, kkg = (r >> 6) & 7, ntile = r >> 9;
        n = ntile * 16 + (l & 15); k = kkg * 32 + ((l >> 4) << 3);
        src = TW1 + (long)d * D2 * T1D; N = T1D;
        dst = TW1P + ((long)(d * 64 + ntile * 8 + kkg) * 64 + l) * 8;
      } else {                    // TW2P: per-domain K=128 (4), N=64 (4)
        int g = t - 73728;
        int d = g >> 10, r = g & 1023;
        int l = r & 63, kkg = (r >> 6) & 3, ntile = r >> 8;
        n = ntile * 16 + (l & 15); k = kkg * 32 + ((l >> 4) << 3);
        src = TW2 + (long)d * T1D * T2D; N = T2D;
        dst = TW2P + ((long)(d * 16 + ntile * 4 + kkg) * 64 + l) * 8;
      }
      bf16x8 o;
#pragma unroll
      for (int e = 0; e < 8; ++e) o[e] = (__bf16)src[(long)(k + e) * N + n];
      *(bf16x8*)dst = o;
    } else if (t < 94208) {       // domain partition (range is wave-aligned)
      int i = t - 77824;
      int d = dom[i];
      int pl = tid & 63;
#pragma unroll
      for (int dd = 0; dd < NDOM; ++dd) {
        unsigned long long md = __ballot(d == dd);
        if (d == dd) {
          int myoff = __popcll(md & ((1ull << pl) - 1ull));
          int leader = __ffsll((long long)md) - 1;
          int base = 0;
          if (pl == leader) base = atomicAdd(&cnt[dd], __popcll(md));
          base = __shfl(base, leader);
          lists[dd * B_SZ + base + myoff] = i;
        }
      }
    }
  }
  grid_barrier(&bar[0]);

  // ================= phase 1: gather + GEMM1 + GEMM2 =================
  {
    int m0 = bid * 64;
    for (int i = tid; i < 64 * F_SZ; i += 512) ids_lds[i] = fids[m0 * F_SZ + i];
    __syncthreads();

    // staging: thread -> (row = tid>>3, 16B chunk sc = tid&7); chunk covers
    // feature 2s+(sc>>2), elems (sc&3)*8.  LDS dest XOR-swizzled by row&7.
    int srow = tid >> 3, sc = tid & 7;
    int sbyte = srow * 128 + ((sc ^ (srow & 7)) << 4);

    // 2-deep prefetch: set A holds step s (even), set B step s+1 (odd)
    float4 g0a, g1a, g0b, g1b;
    {
      int f = 0 + (sc >> 2);
      int id = ids_lds[srow * F_SZ + f];
      const float* p = emb + ((long)f * V_SZ + id) * E_SZ + ((sc & 3) << 3);
      g0a = *(const float4*)p; g1a = *(const float4*)(p + 4);
    }
    {
      int f = 2 + (sc >> 2);
      int id = ids_lds[srow * F_SZ + f];
      const float* p = emb + ((long)f * V_SZ + id) * E_SZ + ((sc & 3) << 3);
      g0b = *(const float4*)p; g1b = *(const float4*)(p + 4);
    }

    f32x4 acc[4][4] = {};

#define GSTEP(S, G0, G1)                                                     \
    {                                                                        \
      bf16x8 o;                                                              \
      o[0]=(__bf16)G0.x; o[1]=(__bf16)G0.y; o[2]=(__bf16)G0.z; o[3]=(__bf16)G0.w; \
      o[4]=(__bf16)G1.x; o[5]=(__bf16)G1.y; o[6]=(__bf16)G1.z; o[7]=(__bf16)G1.w; \
      *(bf16x8*)((char*)(sA + ((S) & 1) * 4096) + sbyte) = o;                \
      if ((S) + 2 < 10) {  /* issue gather for step S+2 into same regs */    \
        int f = 2 * ((S) + 2) + (sc >> 2);                                   \
        int id = ids_lds[srow * F_SZ + f];                                   \
        const float* p = emb + ((long)f * V_SZ + id) * E_SZ + ((sc & 3) << 3); \
        G0 = *(const float4*)p; G1 = *(const float4*)(p + 4);                \
      }                                                                      \
      /* non-draining barrier: order LDS ops only, leave vmem in flight */   \
      asm volatile("s_waitcnt lgkmcnt(0)" ::: "memory");                     \
      __builtin_amdgcn_s_barrier();                                          \
      const char* sAb = (const char*)(sA + ((S) & 1) * 4096);                \
      _Pragma("unroll")                                                      \
      for (int kk = 0; kk < 2; ++kk) {                                       \
        bf16x8 af[4];                                                        \
        _Pragma("unroll")                                                    \
        for (int mi = 0; mi < 4; ++mi) {                                     \
          int byte = ((mi * 16 + lrow) * 128 + (kk * 32 + kq * 8) * 2) ^ ((lrow & 7) << 4); \
          af[mi] = *(const bf16x8*)(sAb + byte);                             \
        }                                                                    \
        _Pragma("unroll")                                                    \
        for (int ni = 0; ni < 4; ++ni) {                                     \
          bf16x8 bfr = *(const bf16x8*)(W1P +                                \
              ((long)((w * 4 + ni) * 20 + ((S) * 2 + kk)) * 64 + lane) * 8); \
          _Pragma("unroll")                                                  \
          for (int mi = 0; mi < 4; ++mi)                                     \
            acc[mi][ni] = MFMA(af[mi], bfr, acc[mi][ni]);                    \
        }                                                                    \
      }                                                                      \
    }

    for (int ss = 0; ss < 5; ++ss) {
      GSTEP(2 * ss,     g0a, g1a)
      GSTEP(2 * ss + 1, g0b, g1b)
    }
#undef GSTEP

    // h1 = relu(. + b1) -> LDS (XOR-swizzled rows, 1024B stride)
#pragma unroll
    for (int ni = 0; ni < 4; ++ni) {
      int col = w * 64 + ni * 16 + lrow;
      float bv = b1[col];
#pragma unroll
      for (int mi = 0; mi < 4; ++mi) {
#pragma unroll
        for (int r = 0; r < 4; ++r) {
          int row = mi * 16 + kq * 4 + r;
          float v = acc[mi][ni][r] + bv;
          v = v > 0.f ? v : 0.f;
          int byte = (row * 1024 + col * 2) ^ ((row & 7) << 4);
          *(__bf16*)((char*)h1 + byte) = (__bf16)v;
        }
      }
    }
    asm volatile("s_waitcnt lgkmcnt(0)" ::: "memory");
    __builtin_amdgcn_s_barrier();

    // GEMM2: h2 = relu(h1 @ W2 + b2), K=512 (16 ksteps)
    f32x4 acc2[4][2] = {};
    for (int kkg = 0; kkg < 16; ++kkg) {
      bf16x8 a2[4];
#pragma unroll
      for (int mi = 0; mi < 4; ++mi) {
        int byte = ((mi * 16 + lrow) * 1024 + kkg * 64 + kq * 16) ^ ((lrow & 7) << 4);
        a2[mi] = *(const bf16x8*)((const char*)h1 + byte);
      }
#pragma unroll
      for (int ni = 0; ni < 2; ++ni) {
        bf16x8 bfr = *(const bf16x8*)(W2P +
            ((long)((w * 2 + ni) * 16 + kkg) * 64 + lane) * 8);
#pragma unroll
        for (int mi = 0; mi < 4; ++mi)
          acc2[mi][ni] = MFMA(a2[mi], bfr, acc2[mi][ni]);
      }
    }

    // h2 store (bf16, bias+relu)
#pragma unroll
    for (int ni = 0; ni < 2; ++ni) {
      int col = w * 32 + ni * 16 + lrow;
      float bv = b2[col];
#pragma unroll
      for (int mi = 0; mi < 4; ++mi) {
#pragma unroll
        for (int r = 0; r < 4; ++r) {
          long row = m0 + mi * 16 + kq * 4 + r;
          float v = acc2[mi][ni][r] + bv;
          v = v > 0.f ? v : 0.f;
          h2[row * D2 + col] = (__bf16)v;
        }
      }
    }
  }
  grid_barrier(&bar[1]);

  // ================= phase 2: towers + sigmoid + select =================
  {
    int d = bid >> 6;            // 64 blocks per domain
    int chunk = bid & 63;
    int nc = cnt[d];
    __bf16* tw = t_lds + w * 2048;   // per-wave 16x128 scratch
    int row = lrow;

    for (int base = chunk * 128; base < nc; base += 64 * 128) {
      int slot = base + w * 16 + row;
      bool valid = slot < nc;
      int m0r = lists[d * B_SZ + (valid ? slot : 0)];

      bf16x8 a1[8];
#pragma unroll
      for (int kk = 0; kk < 8; ++kk)
        a1[kk] = *(const bf16x8*)(h2 + (long)m0r * D2 + kk * 32 + kq * 8);

      // t1 = relu(h2 @ TW1[d] + Tb1[d])  (16 x 128)
      f32x4 acc1[8] = {};
#pragma unroll
      for (int kk = 0; kk < 8; ++kk) {
#pragma unroll
        for (int ni = 0; ni < 8; ++ni) {
          bf16x8 b = *(const bf16x8*)(TW1P +
              ((long)(d * 64 + ni * 8 + kk) * 64 + lane) * 8);
          acc1[ni] = MFMA(a1[kk], b, acc1[ni]);
        }
      }
#pragma unroll
      for (int ni = 0; ni < 8; ++ni) {
        float bv = Tb1[d * T1D + ni * 16 + row];
#pragma unroll
        for (int r = 0; r < 4; ++r) {
          float v = acc1[ni][r] + bv;
          v = v > 0.f ? v : 0.f;
          tw[(kq * 4 + r) * 128 + ni * 16 + row] = (__bf16)v;
        }
      }
      asm volatile("s_waitcnt lgkmcnt(0)" ::: "memory");

      // t2 = relu(t1 @ TW2[d] + Tb2[d])  (16 x 64)
      bf16x8 a2[4];
#pragma unroll
      for (int kk = 0; kk < 4; ++kk)
        a2[kk] = *(const bf16x8*)(&tw[row * 128 + kk * 32 + kq * 8]);
      f32x4 acc2[4] = {};
#pragma unroll
      for (int kk = 0; kk < 4; ++kk) {
#pragma unroll
        for (int ni = 0; ni < 4; ++ni) {
          bf16x8 b = *(const bf16x8*)(TW2P +
              ((long)(d * 16 + ni * 4 + kk) * 64 + lane) * 8);
          acc2[ni] = MFMA(a2[kk], b, acc2[ni]);
        }
      }
      asm volatile("s_waitcnt lgkmcnt(0)" ::: "memory");
#pragma unroll
      for (int ni = 0; ni < 4; ++ni) {
        float bv = Tb2[d * T2D + ni * 16 + row];
#pragma unroll
        for (int r = 0; r < 4; ++r) {
          float v = acc2[ni][r] + bv;
          v = v > 0.f ? v : 0.f;
          tw[(kq * 4 + r) * 64 + ni * 16 + row] = (__bf16)v;
        }
      }
      asm volatile("s_waitcnt lgkmcnt(0)" ::: "memory");

      // logit + sigmoid + store
      float s = 0.f;
#pragma unroll
      for (int j = 0; j < 16; ++j)
        s += (float)tw[row * 64 + kq * 16 + j] * TW3[d * T2D + kq * 16 + j];
      s += __shfl_xor(s, 16);
      s += __shfl_xor(s, 32);
      s += Tb3[d];
      if (valid && kq == 0)
        out[m0r] = 1.0f / (1.0f + expf(-s));
    }
  }
}

// ---------------------------------------------------------------------------
extern "C" void kernel_launch(void* const* d_in, const int* in_sizes, int n_in,
                              void* d_out, int out_size, void* d_ws, size_t ws_size,
                              hipStream_t stream) {
  const int*   fids = (const int*)d_in[0];
  const int*   dom  = (const int*)d_in[1];
  const float* emb  = (const float*)d_in[2];
  const float* W1   = (const float*)d_in[3];
  const float* b1   = (const float*)d_in[4];
  const float* W2   = (const float*)d_in[5];
  const float* b2   = (const float*)d_in[6];
  const float* TW1  = (const float*)d_in[7];
  const float* Tb1  = (const float*)d_in[8];
  const float* TW2  = (const float*)d_in[9];
  const float* Tb2  = (const float*)d_in[10];
  const float* TW3  = (const float*)d_in[11];
  const float* Tb3  = (const float*)d_in[12];
  float* out = (float*)d_out;

  char* ws = (char*)d_ws;
  __bf16* W1P   = (__bf16*)(ws);                 // 655360
  __bf16* W2P   = (__bf16*)(ws + 655360);        // 262144
  __bf16* TW1P  = (__bf16*)(ws + 917504);        // 262144
  __bf16* TW2P  = (__bf16*)(ws + 1179648);       // 65536
  __bf16* h2    = (__bf16*)(ws + 1245184);       // 8388608
  int*    lists = (int*)(ws + 9633792);          // 262144
  int*    cnt   = (int*)(ws + 9895936);          // 16
  int*    bar   = (int*)(ws + 9895952);          // 16

  // zero domain counters + barrier counters (captured in graph; re-runs
  // every replay so the kernel is replay-safe)
  hipMemsetAsync(cnt, 0, 32, stream);

  k_mono<<<256, 512, 0, stream>>>(fids, dom, emb, W1, b1, W2, b2,
                                  TW1, Tb1, TW2, Tb2, TW3, Tb3,
                                  W1P, W2P, TW1P, TW2P, h2, lists, cnt, bar,
                                  out);
}

// Round 6
// 50.878 us; speedup vs baseline: 2.2696x; 2.2696x over previous
//
#include <hip/hip_runtime.h>

#define B_SZ  16384
#define F_SZ  20
#define V_SZ  100000
#define E_SZ  32
#define DBOT  640
#define D1    512
#define D2    256
#define T1D   128
#define T2D   64
#define NDOM  4

typedef __bf16 bf16x8 __attribute__((ext_vector_type(8)));
typedef float  f32x4  __attribute__((ext_vector_type(4)));

#define MFMA(a, b, c) __builtin_amdgcn_mfma_f32_16x16x32_bf16((a), (b), (c), 0, 0, 0)

// ---------------------------------------------------------------------------
// Prep: pack all weights into MFMA-fragment order bf16 (unchanged from R3).
// Block ranges: [0,160) W1P | [160,224) W2P | [224,288) TW1P | [288,304) TW2P
// Block 304 zeroes the domain counters.
// ---------------------------------------------------------------------------
__global__ __launch_bounds__(256) void k_prep(const float* __restrict__ W1,
                                              const float* __restrict__ W2,
                                              const float* __restrict__ TW1,
                                              const float* __restrict__ TW2,
                                              __bf16* __restrict__ W1P,
                                              __bf16* __restrict__ W2P,
                                              __bf16* __restrict__ TW1P,
                                              __bf16* __restrict__ TW2P,
                                              int* __restrict__ cnt) {
  int bid = blockIdx.x, tid = threadIdx.x;
  const float* src; __bf16* dst; int n, k, N;
  if (bid < 160) {           // W1P: K=640 (20 ksteps), N=512 (32 ntiles)
    long g = (long)bid * 256 + tid;
    int lane = g & 63; int kkg = (int)((g >> 6) % 20); int ntile = (int)(g / 1280);
    n = ntile * 16 + (lane & 15); k = kkg * 32 + ((lane >> 4) << 3);
    src = W1; N = D1; dst = W1P + g * 8;
  } else if (bid < 224) {    // W2P: K=512 (16), N=256 (16)
    long g = (long)(bid - 160) * 256 + tid;
    int lane = g & 63; int kkg = (int)((g >> 6) & 15); int ntile = (int)(g >> 10);
    n = ntile * 16 + (lane & 15); k = kkg * 32 + ((lane >> 4) << 3);
    src = W2; N = D2; dst = W2P + g * 8;
  } else if (bid < 288) {    // TW1P: per-domain K=256 (8), N=128 (8)
    long g = (long)(bid - 224) * 256 + tid;
    int d = (int)(g >> 12); long r = g & 4095;
    int lane = r & 63; int kkg = (int)((r >> 6) & 7); int ntile = (int)(r >> 9);
    n = ntile * 16 + (lane & 15); k = kkg * 32 + ((lane >> 4) << 3);
    src = TW1 + (long)d * D2 * T1D; N = T1D;
    dst = TW1P + ((long)(d * 64 + ntile * 8 + kkg) * 64 + lane) * 8;
  } else if (bid < 304) {    // TW2P: per-domain K=128 (4), N=64 (4)
    long g = (long)(bid - 288) * 256 + tid;
    int d = (int)(g >> 10); long r = g & 1023;
    int lane = r & 63; int kkg = (int)((r >> 6) & 3); int ntile = (int)(r >> 8);
    n = ntile * 16 + (lane & 15); k = kkg * 32 + ((lane >> 4) << 3);
    src = TW2 + (long)d * T1D * T2D; N = T2D;
    dst = TW2P + ((long)(d * 16 + ntile * 4 + kkg) * 64 + lane) * 8;
  } else {
    if (tid < NDOM) cnt[tid] = 0;
    return;
  }
  bf16x8 o;
#pragma unroll
  for (int e = 0; e < 8; ++e) o[e] = (__bf16)src[(long)(k + e) * N + n];
  *(bf16x8*)dst = o;
}

// ---------------------------------------------------------------------------
// Fused: gather + GEMM1 + GEMM2 per 64-row panel (R3 macro-structure).
// New K-loop: non-draining lgkm-only barriers + sched fence, B-frag register
// double-buffer, 2-deep gather prefetch.  Issue order per step keeps gathers
// the YOUNGEST vmem ops so no B-frag wait force-drains them (vmcnt retires
// in order); gathers ride ~2 MFMA sections (~HBM latency) in flight.
// ---------------------------------------------------------------------------
__global__ __launch_bounds__(512, 2) void k_fused(const int* __restrict__ fids,
                                                  const int* __restrict__ dom,
                                                  const float* __restrict__ emb,
                                                  const __bf16* __restrict__ W1P,
                                                  const float* __restrict__ b1,
                                                  const __bf16* __restrict__ W2P,
                                                  const float* __restrict__ b2,
                                                  __bf16* __restrict__ h2,
                                                  int* __restrict__ cnt,
                                                  int* __restrict__ lists) {
  __shared__ int    ids_lds[64 * F_SZ];
  __shared__ __bf16 sA[2][64 * 64];
  __shared__ __bf16 h1[64 * D1];

  int bid = blockIdx.x, tid = threadIdx.x;
  int lane = tid & 63, w = tid >> 6;
  int lrow = lane & 15, kq = lane >> 4;
  int m0 = bid * 64;

  // ---- domain partition (blocks 0-63, first 4 waves) ----
  if (bid < 64 && tid < 256) {
    int i = bid * 256 + tid;
    int d = dom[i];
    int pl = tid & 63;
#pragma unroll
    for (int dd = 0; dd < NDOM; ++dd) {
      unsigned long long md = __ballot(d == dd);
      if (d == dd) {
        int myoff = __popcll(md & ((1ull << pl) - 1ull));
        int leader = __ffsll((long long)md) - 1;
        int base = 0;
        if (pl == leader) base = atomicAdd(&cnt[dd], __popcll(md));
        base = __shfl(base, leader);
        lists[dd * B_SZ + base + myoff] = i;
      }
    }
  }

  // ---- stage feature ids ----
  for (int i = tid; i < 64 * F_SZ; i += 512) ids_lds[i] = fids[m0 * F_SZ + i];
  __syncthreads();

  // staging: thread -> (row = tid>>3, 16B chunk sc = tid&7); chunk covers
  // feature 2s+(sc>>2), elems (sc&3)*8.  LDS dest XOR-swizzled by row&7.
  int srow = tid >> 3, sc = tid & 7;
  int sbyte = srow * 128 + ((sc ^ (srow & 7)) << 4);
  int fsub = sc >> 2, esub = (sc & 3) << 3;

  // prologue: gather sets for steps 0 (A) and 1 (B); B-frags for step 0
  float4 g0a, g1a, g0b, g1b;
  {
    int id = ids_lds[srow * F_SZ + fsub];
    const float* p = emb + ((long)fsub * V_SZ + id) * E_SZ + esub;
    g0a = *(const float4*)p; g1a = *(const float4*)(p + 4);
  }
  {
    int id = ids_lds[srow * F_SZ + 2 + fsub];
    const float* p = emb + ((long)(2 + fsub) * V_SZ + id) * E_SZ + esub;
    g0b = *(const float4*)p; g1b = *(const float4*)(p + 4);
  }
  bf16x8 bfA[8], bfB[8];
#pragma unroll
  for (int ni = 0; ni < 4; ++ni)
#pragma unroll
    for (int kk = 0; kk < 2; ++kk)
      bfA[ni * 2 + kk] = *(const bf16x8*)(W1P +
          ((long)((w * 4 + ni) * 20 + kk) * 64 + lane) * 8);

  f32x4 acc[4][4] = {};

#define BODY(S, G0, G1, BC, BN)                                              \
    {                                                                        \
      bf16x8 o;                                                              \
      o[0]=(__bf16)G0.x; o[1]=(__bf16)G0.y; o[2]=(__bf16)G0.z; o[3]=(__bf16)G0.w; \
      o[4]=(__bf16)G1.x; o[5]=(__bf16)G1.y; o[6]=(__bf16)G1.z; o[7]=(__bf16)G1.w; \
      *(bf16x8*)((char*)sA + ((S) & 1) * 8192 + sbyte) = o;                  \
      asm volatile("s_waitcnt lgkmcnt(0)" ::: "memory");                     \
      __builtin_amdgcn_s_barrier();                                          \
      __builtin_amdgcn_sched_barrier(0);                                     \
      const char* sAb = (const char*)sA + ((S) & 1) * 8192;                  \
      bf16x8 af[2][4];                                                       \
      _Pragma("unroll")                                                      \
      for (int kk = 0; kk < 2; ++kk)                                         \
        _Pragma("unroll")                                                    \
        for (int mi = 0; mi < 4; ++mi) {                                     \
          int byte = ((mi * 16 + lrow) * 128 + (kk * 32 + kq * 8) * 2) ^ ((lrow & 7) << 4); \
          af[kk][mi] = *(const bf16x8*)(sAb + byte);                         \
        }                                                                    \
      _Pragma("unroll")                                                      \
      for (int kk = 0; kk < 2; ++kk)                                         \
        _Pragma("unroll")                                                    \
        for (int ni = 0; ni < 4; ++ni)                                       \
          _Pragma("unroll")                                                  \
          for (int mi = 0; mi < 4; ++mi)                                     \
            acc[mi][ni] = MFMA(af[kk][mi], BC[ni * 2 + kk], acc[mi][ni]);    \
      if ((S) + 1 < 10) {  /* prefetch next step's B-frags (older than gathers) */ \
        _Pragma("unroll")                                                    \
        for (int ni = 0; ni < 4; ++ni)                                       \
          _Pragma("unroll")                                                  \
          for (int kk = 0; kk < 2; ++kk)                                     \
            BN[ni * 2 + kk] = *(const bf16x8*)(W1P +                         \
                ((long)((w * 4 + ni) * 20 + ((S) + 1) * 2 + kk) * 64 + lane) * 8); \
      }                                                                      \
      if ((S) + 2 < 10) {  /* issue gathers for step S+2 (youngest vmem) */  \
        int f = 2 * ((S) + 2) + fsub;                                        \
        int id = ids_lds[srow * F_SZ + f];                                   \
        const float* p = emb + ((long)f * V_SZ + id) * E_SZ + esub;          \
        G0 = *(const float4*)p; G1 = *(const float4*)(p + 4);                \
      }                                                                      \
    }

  BODY(0, g0a, g1a, bfA, bfB)
  BODY(1, g0b, g1b, bfB, bfA)
  BODY(2, g0a, g1a, bfA, bfB)
  BODY(3, g0b, g1b, bfB, bfA)
  BODY(4, g0a, g1a, bfA, bfB)
  BODY(5, g0b, g1b, bfB, bfA)
  BODY(6, g0a, g1a, bfA, bfB)
  BODY(7, g0b, g1b, bfB, bfA)
  BODY(8, g0a, g1a, bfA, bfB)
  BODY(9, g0b, g1b, bfB, bfA)
#undef BODY

  // ---- h1 = relu(. + b1) -> LDS (XOR-swizzled rows, 1024B stride) ----
#pragma unroll
  for (int ni = 0; ni < 4; ++ni) {
    int col = w * 64 + ni * 16 + lrow;
    float bv = b1[col];
#pragma unroll
    for (int mi = 0; mi < 4; ++mi) {
#pragma unroll
      for (int r = 0; r < 4; ++r) {
        int row = mi * 16 + kq * 4 + r;
        float v = acc[mi][ni][r] + bv;
        v = v > 0.f ? v : 0.f;
        int byte = (row * 1024 + col * 2) ^ ((row & 7) << 4);
        *(__bf16*)((char*)h1 + byte) = (__bf16)v;
      }
    }
  }
  __syncthreads();

  // ---- GEMM2: h2 = relu(h1 @ W2 + b2), K=512 (16 ksteps) ----
  f32x4 acc2[4][2] = {};
  for (int kkg = 0; kkg < 16; ++kkg) {
    bf16x8 a2[4];
#pragma unroll
    for (int mi = 0; mi < 4; ++mi) {
      int byte = ((mi * 16 + lrow) * 1024 + kkg * 64 + kq * 16) ^ ((lrow & 7) << 4);
      a2[mi] = *(const bf16x8*)((const char*)h1 + byte);
    }
#pragma unroll
    for (int ni = 0; ni < 2; ++ni) {
      bf16x8 bfr = *(const bf16x8*)(W2P +
          ((long)((w * 2 + ni) * 16 + kkg) * 64 + lane) * 8);
#pragma unroll
      for (int mi = 0; mi < 4; ++mi)
        acc2[mi][ni] = MFMA(a2[mi], bfr, acc2[mi][ni]);
    }
  }

  // ---- h2 store (bf16, bias+relu) ----
#pragma unroll
  for (int ni = 0; ni < 2; ++ni) {
    int col = w * 32 + ni * 16 + lrow;
    float bv = b2[col];
#pragma unroll
    for (int mi = 0; mi < 4; ++mi) {
#pragma unroll
      for (int r = 0; r < 4; ++r) {
        long row = m0 + mi * 16 + kq * 4 + r;
        float v = acc2[mi][ni][r] + bv;
        v = v > 0.f ? v : 0.f;
        h2[row * D2 + col] = (__bf16)v;
      }
    }
  }
}

// ---------------------------------------------------------------------------
// Tower (domain-partitioned): unchanged from R3.
// ---------------------------------------------------------------------------
__global__ __launch_bounds__(256) void k_tower(const __bf16* __restrict__ h2,
                                               const __bf16* __restrict__ TW1P,
                                               const __bf16* __restrict__ TW2P,
                                               const float* __restrict__ Tb1,
                                               const float* __restrict__ Tb2,
                                               const float* __restrict__ TW3,
                                               const float* __restrict__ Tb3,
                                               const int* __restrict__ cnt,
                                               const int* __restrict__ lists,
                                               float* __restrict__ out) {
  __shared__ __bf16 t_lds[4][16 * 128];
  int d  = blockIdx.y;
  int nc = cnt[d];
  int base = blockIdx.x * 64;
  if (base >= nc) return;

  int tid  = threadIdx.x;
  int lane = tid & 63;
  int w    = tid >> 6;
  int row  = lane & 15;
  int kq   = lane >> 4;
  int slot = base + w * 16 + row;
  bool valid = slot < nc;
  int m0r = lists[d * B_SZ + (valid ? slot : 0)];

  bf16x8 a1[8];
#pragma unroll
  for (int kk = 0; kk < 8; ++kk)
    a1[kk] = *(const bf16x8*)(h2 + (long)m0r * D2 + kk * 32 + kq * 8);

  // t1 = relu(h2 @ TW1[d] + Tb1[d])
  f32x4 acc1[8] = {};
#pragma unroll
  for (int kk = 0; kk < 8; ++kk) {
#pragma unroll
    for (int ni = 0; ni < 8; ++ni) {
      bf16x8 b = *(const bf16x8*)(TW1P +
          ((long)(d * 64 + ni * 8 + kk) * 64 + lane) * 8);
      acc1[ni] = MFMA(a1[kk], b, acc1[ni]);
    }
  }
#pragma unroll
  for (int ni = 0; ni < 8; ++ni) {
    float bv = Tb1[d * T1D + ni * 16 + row];
#pragma unroll
    for (int r = 0; r < 4; ++r) {
      float v = acc1[ni][r] + bv;
      v = v > 0.f ? v : 0.f;
      t_lds[w][(kq * 4 + r) * 128 + ni * 16 + row] = (__bf16)v;
    }
  }
  asm volatile("s_waitcnt lgkmcnt(0)" ::: "memory");

  // t2 = relu(t1 @ TW2[d] + Tb2[d])
  bf16x8 a2[4];
#pragma unroll
  for (int kk = 0; kk < 4; ++kk)
    a2[kk] = *(const bf16x8*)(&t_lds[w][row * 128 + kk * 32 + kq * 8]);
  f32x4 acc2[4] = {};
#pragma unroll
  for (int kk = 0; kk < 4; ++kk) {
#pragma unroll
    for (int ni = 0; ni < 4; ++ni) {
      bf16x8 b = *(const bf16x8*)(TW2P +
          ((long)(d * 16 + ni * 4 + kk) * 64 + lane) * 8);
      acc2[ni] = MFMA(a2[kk], b, acc2[ni]);
    }
  }
  asm volatile("s_waitcnt lgkmcnt(0)" ::: "memory");
#pragma unroll
  for (int ni = 0; ni < 4; ++ni) {
    float bv = Tb2[d * T2D + ni * 16 + row];
#pragma unroll
    for (int r = 0; r < 4; ++r) {
      float v = acc2[ni][r] + bv;
      v = v > 0.f ? v : 0.f;
      t_lds[w][(kq * 4 + r) * 64 + ni * 16 + row] = (__bf16)v;
    }
  }
  asm volatile("s_waitcnt lgkmcnt(0)" ::: "memory");

  // logit + sigmoid + store
  float s = 0.f;
#pragma unroll
  for (int j = 0; j < 16; ++j)
    s += (float)t_lds[w][row * 64 + kq * 16 + j] * TW3[d * T2D + kq * 16 + j];
  s += __shfl_xor(s, 16);
  s += __shfl_xor(s, 32);
  s += Tb3[d];
  if (valid && kq == 0)
    out[m0r] = 1.0f / (1.0f + expf(-s));
}

// ---------------------------------------------------------------------------
extern "C" void kernel_launch(void* const* d_in, const int* in_sizes, int n_in,
                              void* d_out, int out_size, void* d_ws, size_t ws_size,
                              hipStream_t stream) {
  const int*   fids = (const int*)d_in[0];
  const int*   dom  = (const int*)d_in[1];
  const float* emb  = (const float*)d_in[2];
  const float* W1   = (const float*)d_in[3];
  const float* b1   = (const float*)d_in[4];
  const float* W2   = (const float*)d_in[5];
  const float* b2   = (const float*)d_in[6];
  const float* TW1  = (const float*)d_in[7];
  const float* Tb1  = (const float*)d_in[8];
  const float* TW2  = (const float*)d_in[9];
  const float* Tb2  = (const float*)d_in[10];
  const float* TW3  = (const float*)d_in[11];
  const float* Tb3  = (const float*)d_in[12];
  float* out = (float*)d_out;

  char* ws = (char*)d_ws;
  __bf16* W1P   = (__bf16*)(ws);                 // 655360
  __bf16* W2P   = (__bf16*)(ws + 655360);        // 262144
  __bf16* TW1P  = (__bf16*)(ws + 917504);        // 262144
  __bf16* TW2P  = (__bf16*)(ws + 1179648);       // 65536
  __bf16* h2    = (__bf16*)(ws + 1245184);       // 8388608
  int*    lists = (int*)(ws + 9633792);          // 262144
  int*    cnt   = (int*)(ws + 9895936);          // 16

  // 1) pack weights + zero counters
  k_prep<<<305, 256, 0, stream>>>(W1, W2, TW1, TW2, W1P, W2P, TW1P, TW2P, cnt);

  // 2) fused gather + GEMM1 + GEMM2 (+ partition in blocks 0-63)
  k_fused<<<256, 512, 0, stream>>>(fids, dom, emb, W1P, b1, W2P, b2, h2,
                                   cnt, lists);

  // 3) towers + sigmoid + select
  k_tower<<<dim3(80, NDOM), 256, 0, stream>>>(h2, TW1P, TW2P, Tb1, Tb2,
                                              TW3, Tb3, cnt, lists, out);
}